// Round 4
// baseline (422.527 us; speedup 1.0000x reference)
//
#include <hip/hip_runtime.h>

#define TOKENS 32768
#define DIN 1024
#define DOUT 1024
#define RANK 16
#define SCALE1 0.5f
#define SCALE2 1.0f

#define BM 128
#define BN 128
#define BK 32

typedef __bf16 bf16x8 __attribute__((ext_vector_type(8)));
typedef float f32x4 __attribute__((ext_vector_type(4)));

// Async global->LDS, 16B per lane. LDS dest is wave-uniform base + lane*16.
__device__ __forceinline__ void load_lds16(const void* gptr, void* lptr) {
    __builtin_amdgcn_global_load_lds(
        (__attribute__((address_space(1))) void*)gptr,
        (__attribute__((address_space(3))) void*)lptr, 16, 0, 0);
}

__device__ __forceinline__ void store_cvt(__bf16* dst, float4 a, float4 b) {
    bf16x8 v;
    v[0] = (__bf16)a.x; v[1] = (__bf16)a.y; v[2] = (__bf16)a.z; v[3] = (__bf16)a.w;
    v[4] = (__bf16)b.x; v[5] = (__bf16)b.y; v[6] = (__bf16)b.z; v[7] = (__bf16)b.w;
    *(bf16x8*)dst = v;
}

// ---------------------------------------------------------------------------
// Kernel 1: Weff = W + 0.5*B1@A1 + 1.0*B2@A2, cast to bf16.  [DOUT, DIN]
// ---------------------------------------------------------------------------
__global__ void weff_kernel(const float* __restrict__ W, const float* __restrict__ A1,
                            const float* __restrict__ B1, const float* __restrict__ A2,
                            const float* __restrict__ B2, __bf16* __restrict__ Weff) {
    int idx = blockIdx.x * blockDim.x + threadIdx.x;  // over DOUT*DIN
    int o = idx >> 10;
    int i = idx & 1023;
    float s1 = 0.f, s2 = 0.f;
#pragma unroll
    for (int r = 0; r < RANK; ++r) {
        s1 += B1[o * RANK + r] * A1[r * DIN + i];
        s2 += B2[o * RANK + r] * A2[r * DIN + i];
    }
    Weff[idx] = (__bf16)(W[idx] + SCALE1 * s1 + SCALE2 * s2);
}

// ---------------------------------------------------------------------------
// Kernel 2 (GEMM): out[M,N] = cvt_bf16(X)[M,K] @ Weff[N,K]^T + bias.
//
// R1: XOR chunk swizzle (phys chunk = log chunk ^ ((row>>1)&3)) -> 0 LDS bank
//     conflicts (verified).
// R2: double-buffered LDS, one barrier/iter.
// R4: (a) fp32->bf16 conversion FUSED into A-staging (cvt_x kernel deleted):
//         X fp32 -> VGPR at iteration top, cvt + ds_write after the compute
//         phase, so the global-load latency is covered by MFMA+ds_read work.
//     (b) B (Weff) stays on the global_load_lds DMA path, prefetched into
//         the back buffer right after the barrier -> a full compute phase in
//         flight before the next barrier's vmcnt drain.
//     (c) XCD-aware block swizzle: xcd = id&7 owns a contiguous 32-mtile
//         stripe, n fastest -> the 8 blocks sharing an A-tile are temporally
//         adjacent on ONE XCD (A-tile L2-resident), Weff (2MB) resident per
//         XCD L2. Targets the 4x A over-fetch (FETCH 269 MB vs ideal 66).
// ---------------------------------------------------------------------------
__global__ __launch_bounds__(256) void gemm_bt_kernel(
    const float* __restrict__ X,    // [TOKENS, DIN] fp32
    const __bf16* __restrict__ Bw,  // [DOUT, DIN] bf16
    const float* __restrict__ bias, float* __restrict__ C) {
    __shared__ alignas(16) __bf16 lsA[2][BM * BK];  // 2 x 8 KB
    __shared__ alignas(16) __bf16 lsB[2][BN * BK];  // 2 x 8 KB

    const int tid = threadIdx.x;
    const int wave = tid >> 6;
    const int lane = tid & 63;

    // XCD-aware swizzle (assignment heuristic: linear id -> xcd round-robin).
    const int l = blockIdx.x;
    const int xcd = l & 7;
    const int s = l >> 3;
    const int m0 = (xcd * 32 + (s >> 3)) * BM;  // contiguous m-stripe per XCD
    const int n0 = (s & 7) * BN;                // n fastest: A-tile temporal reuse

    const int wm = wave >> 1;  // 0..1
    const int wn = wave & 1;   // 0..1

    // ---- A staging (fused cvt): thread t handles rows t>>2 and t>>2 + 64,
    //      16B chunk t&3. Swizzle invariant under row+64.
    const int arow = tid >> 2;  // 0..63
    const int ach = tid & 3;
    const float* pA = X + (size_t)(m0 + arow) * DIN + ach * 8;
    const int aoff = arow * BK + (ach ^ ((arow >> 1) & 3)) * 8;

    // ---- B staging (lds-DMA): lane l covers row l>>2 of a 16-row slab;
    //      fetches logical chunk (l&3)^((l>>3)&3) -> lands swizzled.
    const int lrow = lane >> 2;
    const int lcol = ((lane & 3) ^ ((lane >> 3) & 3)) * 8;
    const __bf16* gB = Bw + (size_t)(n0 + wave * 32 + lrow) * DIN + lcol;
    const int so0 = (wave * 32) * BK;
    const int so1 = so0 + 16 * BK;

    f32x4 acc[4][4];
#pragma unroll
    for (int i = 0; i < 4; ++i)
#pragma unroll
        for (int j = 0; j < 4; ++j) acc[i][j] = f32x4{0.f, 0.f, 0.f, 0.f};

    // Fragment addressing: A[m=lane&15][k=(lane>>4)*8+j]; phys chunk XOR'd.
    const int fr = lane & 15;
    const int fsw = ((lane >> 4) ^ ((lane >> 1) & 3)) * 8;

    // ---- Prologue: stage tile k=0 into buffer 0.
    {
        float4 u0 = *(const float4*)(pA);
        float4 v0 = *(const float4*)(pA + 4);
        float4 u1 = *(const float4*)(pA + (size_t)64 * DIN);
        float4 v1 = *(const float4*)(pA + (size_t)64 * DIN + 4);
        store_cvt(&lsA[0][aoff], u0, v0);
        store_cvt(&lsA[0][aoff + 64 * BK], u1, v1);
        load_lds16(gB, &lsB[0][so0]);
        load_lds16(gB + 16 * DIN, &lsB[0][so1]);
    }
    __syncthreads();

    int cur = 0;
    for (int k0 = 0; k0 < DIN; k0 += BK) {
        const bool more = (k0 + BK) < DIN;
        float4 u0, v0, u1, v1;
        if (more) {
            // Issue next A-tile fp32 loads FIRST (consumed after compute),
            // then B-DMA into the back buffer (drained at next barrier,
            // a full compute phase later).
            const float* p = pA + k0 + BK;
            u0 = *(const float4*)(p);
            v0 = *(const float4*)(p + 4);
            u1 = *(const float4*)(p + (size_t)64 * DIN);
            v1 = *(const float4*)(p + (size_t)64 * DIN + 4);
            load_lds16(gB + k0 + BK, &lsB[cur ^ 1][so0]);
            load_lds16(gB + k0 + BK + 16 * DIN, &lsB[cur ^ 1][so1]);
        }

        bf16x8 af[4], bfv[4];
#pragma unroll
        for (int t = 0; t < 4; ++t) {
            af[t] = *(const bf16x8*)&lsA[cur][(wm * 64 + t * 16 + fr) * BK + fsw];
            bfv[t] = *(const bf16x8*)&lsB[cur][(wn * 64 + t * 16 + fr) * BK + fsw];
        }
#pragma unroll
        for (int mt = 0; mt < 4; ++mt)
#pragma unroll
            for (int nt = 0; nt < 4; ++nt)
                acc[mt][nt] = __builtin_amdgcn_mfma_f32_16x16x32_bf16(
                    af[mt], bfv[nt], acc[mt][nt], 0, 0, 0);

        if (more) {
            store_cvt(&lsA[cur ^ 1][aoff], u0, v0);
            store_cvt(&lsA[cur ^ 1][aoff + 64 * BK], u1, v1);
            __syncthreads();  // all reads of buf[cur] done; nxt staging drained
        }
        cur ^= 1;
    }

    // Epilogue: C/D layout col = lane&15, row = (lane>>4)*4 + reg.
    const int rbase = (lane >> 4) * 4;
#pragma unroll
    for (int nt = 0; nt < 4; ++nt) {
        const int n = n0 + wn * 64 + nt * 16 + fr;
        const float bv = bias[n];
#pragma unroll
        for (int mt = 0; mt < 4; ++mt) {
            const int m = m0 + wm * 64 + mt * 16 + rbase;
            float* cp = C + (size_t)m * DOUT + n;
#pragma unroll
            for (int r = 0; r < 4; ++r) cp[(size_t)r * DOUT] = acc[mt][nt][r] + bv;
        }
    }
}

// ---------------------------------------------------------------------------
extern "C" void kernel_launch(void* const* d_in, const int* in_sizes, int n_in,
                              void* d_out, int out_size, void* d_ws, size_t ws_size,
                              hipStream_t stream) {
    const float* x  = (const float*)d_in[0];
    const float* W  = (const float*)d_in[1];
    const float* b  = (const float*)d_in[2];
    const float* A1 = (const float*)d_in[3];
    const float* B1 = (const float*)d_in[4];
    const float* A2 = (const float*)d_in[5];
    const float* B2 = (const float*)d_in[6];
    float* out = (float*)d_out;

    // Workspace: [Weff_bf16: 2 MB]
    __bf16* Weff = (__bf16*)d_ws;

    weff_kernel<<<DOUT * DIN / 256, 256, 0, stream>>>(W, A1, B1, A2, B2, Weff);
    gemm_bt_kernel<<<(TOKENS / BM) * (DOUT / BN), 256, 0, stream>>>(x, Weff, b, out);
}

// Round 5
// 329.933 us; speedup vs baseline: 1.2806x; 1.2806x over previous
//
#include <hip/hip_runtime.h>

#define TOKENS 32768
#define DIN 1024
#define DOUT 1024
#define RANK 16
#define SCALE1 0.5f
#define SCALE2 1.0f

#define BM 128
#define BN 128
#define BK 32

typedef __bf16 bf16x8 __attribute__((ext_vector_type(8)));
typedef float f32x4 __attribute__((ext_vector_type(4)));

// Async global->LDS, 16B per lane. LDS dest is wave-uniform base + lane*16.
__device__ __forceinline__ void load_lds16(const void* gptr, void* lptr) {
    __builtin_amdgcn_global_load_lds(
        (__attribute__((address_space(1))) void*)gptr,
        (__attribute__((address_space(3))) void*)lptr, 16, 0, 0);
}

// ---------------------------------------------------------------------------
// Kernel 1: Weff = W + 0.5*B1@A1 + 1.0*B2@A2, cast to bf16.  [DOUT, DIN]
// ---------------------------------------------------------------------------
__global__ void weff_kernel(const float* __restrict__ W, const float* __restrict__ A1,
                            const float* __restrict__ B1, const float* __restrict__ A2,
                            const float* __restrict__ B2, __bf16* __restrict__ Weff) {
    int idx = blockIdx.x * blockDim.x + threadIdx.x;  // over DOUT*DIN
    int o = idx >> 10;
    int i = idx & 1023;
    float s1 = 0.f, s2 = 0.f;
#pragma unroll
    for (int r = 0; r < RANK; ++r) {
        s1 += B1[o * RANK + r] * A1[r * DIN + i];
        s2 += B2[o * RANK + r] * A2[r * DIN + i];
    }
    Weff[idx] = (__bf16)(W[idx] + SCALE1 * s1 + SCALE2 * s2);
}

// ---------------------------------------------------------------------------
// Kernel 2: x fp32 -> bf16, 8 elems/thread, 16B stores. (R4's fused variant
// put HBM latency on the GEMM critical path -> 250us; separate pass is
// streaming-bound ~30us. Keep separate.)
// ---------------------------------------------------------------------------
__global__ void cvt_x_kernel(const float* __restrict__ x, __bf16* __restrict__ xb) {
    int i = (blockIdx.x * blockDim.x + threadIdx.x) * 8;
    float4 a = *(const float4*)(x + i);
    float4 b = *(const float4*)(x + i + 4);
    bf16x8 v;
    v[0] = (__bf16)a.x; v[1] = (__bf16)a.y; v[2] = (__bf16)a.z; v[3] = (__bf16)a.w;
    v[4] = (__bf16)b.x; v[5] = (__bf16)b.y; v[6] = (__bf16)b.z; v[7] = (__bf16)b.w;
    *(bf16x8*)(xb + i) = v;
}

// ---------------------------------------------------------------------------
// Kernel 3: out[M,N] = A[M,K] @ Bw[N,K]^T + bias.  128x128 tile.
//
// R1: XOR chunk swizzle (phys chunk = log chunk ^ ((row>>1)&3)) -> 0 LDS bank
//     conflicts (verified).
// R2/R3: double-buffered LDS + cross-iter DMA prefetch, one barrier/iter.
// R5: XCD-aware block swizzle ONLY from R4 (verified FETCH 269->98 MB);
//     staging reverted to the all-DMA bf16 path (R4's fused fp32 cvt exposed
//     HBM latency on the critical path: 250us).
// ---------------------------------------------------------------------------
__global__ __launch_bounds__(256) void gemm_bt_kernel(
    const __bf16* __restrict__ A,   // [TOKENS, DIN] bf16
    const __bf16* __restrict__ Bw,  // [DOUT, DIN] bf16
    const float* __restrict__ bias, float* __restrict__ C) {
    __shared__ alignas(16) __bf16 lsA[2][BM * BK];  // 2 x 8 KB
    __shared__ alignas(16) __bf16 lsB[2][BN * BK];  // 2 x 8 KB

    const int tid = threadIdx.x;
    const int wave = tid >> 6;
    const int lane = tid & 63;

    // XCD-aware swizzle (dispatch heuristic: linear id -> xcd round-robin).
    // xcd owns a contiguous 32-mtile stripe; n fastest within it, so the 8
    // blocks sharing an A-tile are temporally adjacent on ONE XCD and Weff
    // (2 MB) stays resident in each XCD's 4 MB L2.
    const int l = blockIdx.x;
    const int xcd = l & 7;
    const int s = l >> 3;
    const int m0 = (xcd * 32 + (s >> 3)) * BM;
    const int n0 = (s & 7) * BN;

    const int wm = wave >> 1;  // 0..1
    const int wn = wave & 1;   // 0..1

    // Staging: lane l covers row l>>2 of a 16-row slab; fetches logical chunk
    // (l&3) ^ ((l>>3)&3) so it lands at physical chunk l&3 under the swizzle.
    const int lrow = lane >> 2;
    const int lcol = ((lane & 3) ^ ((lane >> 3) & 3)) * 8;  // element offset

    const __bf16* gA = A + (size_t)(m0 + wave * 32 + lrow) * DIN + lcol;
    const __bf16* gB = Bw + (size_t)(n0 + wave * 32 + lrow) * DIN + lcol;
    const int so0 = (wave * 32) * BK;        // LDS elem offset, slab rows 0-15
    const int so1 = so0 + 16 * BK;           // slab rows 16-31

    f32x4 acc[4][4];
#pragma unroll
    for (int i = 0; i < 4; ++i)
#pragma unroll
        for (int j = 0; j < 4; ++j) acc[i][j] = f32x4{0.f, 0.f, 0.f, 0.f};

    // Fragment addressing: A[m=lane&15][k=(lane>>4)*8+j].
    // Physical chunk = (lane>>4) ^ ((fr>>1)&3), fr = lane&15.
    const int fr = lane & 15;
    const int fsw = ((lane >> 4) ^ ((lane >> 1) & 3)) * 8;  // swizzled elem offset

    // Prologue: stage tile 0 into buffer 0.
    load_lds16(gA, &lsA[0][so0]);
    load_lds16(gA + 16 * DIN, &lsA[0][so1]);
    load_lds16(gB, &lsB[0][so0]);
    load_lds16(gB + 16 * DIN, &lsB[0][so1]);

    int cur = 0;
    for (int k0 = 0; k0 < DIN; k0 += BK) {
        __syncthreads();  // drains buf[cur] staging (in flight since last iter)

        if (k0 + BK < DIN) {  // prefetch next tile into the other buffer
            const int kn = k0 + BK;
            load_lds16(gA + kn, &lsA[cur ^ 1][so0]);
            load_lds16(gA + kn + 16 * DIN, &lsA[cur ^ 1][so1]);
            load_lds16(gB + kn, &lsB[cur ^ 1][so0]);
            load_lds16(gB + kn + 16 * DIN, &lsB[cur ^ 1][so1]);
        }

        bf16x8 af[4], bfv[4];
#pragma unroll
        for (int t = 0; t < 4; ++t) {
            af[t] = *(const bf16x8*)&lsA[cur][(wm * 64 + t * 16 + fr) * BK + fsw];
            bfv[t] = *(const bf16x8*)&lsB[cur][(wn * 64 + t * 16 + fr) * BK + fsw];
        }
#pragma unroll
        for (int mt = 0; mt < 4; ++mt)
#pragma unroll
            for (int nt = 0; nt < 4; ++nt)
                acc[mt][nt] = __builtin_amdgcn_mfma_f32_16x16x32_bf16(
                    af[mt], bfv[nt], acc[mt][nt], 0, 0, 0);
        cur ^= 1;
    }

    // Epilogue: C/D layout col = lane&15, row = (lane>>4)*4 + reg.
    const int rbase = (lane >> 4) * 4;
#pragma unroll
    for (int nt = 0; nt < 4; ++nt) {
        const int n = n0 + wn * 64 + nt * 16 + fr;
        const float bv = bias[n];
#pragma unroll
        for (int mt = 0; mt < 4; ++mt) {
            const int m = m0 + wm * 64 + mt * 16 + rbase;
            float* cp = C + (size_t)m * DOUT + n;
#pragma unroll
            for (int r = 0; r < 4; ++r) cp[(size_t)r * DOUT] = acc[mt][nt][r] + bv;
        }
    }
}

// ---------------------------------------------------------------------------
extern "C" void kernel_launch(void* const* d_in, const int* in_sizes, int n_in,
                              void* d_out, int out_size, void* d_ws, size_t ws_size,
                              hipStream_t stream) {
    const float* x  = (const float*)d_in[0];
    const float* W  = (const float*)d_in[1];
    const float* b  = (const float*)d_in[2];
    const float* A1 = (const float*)d_in[3];
    const float* B1 = (const float*)d_in[4];
    const float* A2 = (const float*)d_in[5];
    const float* B2 = (const float*)d_in[6];
    float* out = (float*)d_out;

    // Workspace: [x_bf16: 64 MB][Weff_bf16: 2 MB]
    __bf16* xb   = (__bf16*)d_ws;
    __bf16* Weff = (__bf16*)((char*)d_ws + (size_t)TOKENS * DIN * sizeof(__bf16));

    cvt_x_kernel<<<TOKENS * DIN / (256 * 8), 256, 0, stream>>>(x, xb);
    weff_kernel<<<DOUT * DIN / 256, 256, 0, stream>>>(W, A1, B1, A2, B2, Weff);
    gemm_bt_kernel<<<(TOKENS / BM) * (DOUT / BN), 256, 0, stream>>>(xb, Weff, b, out);
}